// Round 4
// baseline (207.486 us; speedup 1.0000x reference)
//
#include <hip/hip_runtime.h>

#define T_SEQ   2048
#define DM      2048
#define N_Q     16
#define N_KV    4
#define HD      128
#define WIN     512
#define NB      2
#define NQKV    3072
// 1/sqrt(128) * log2(e): attention computed in exp2 domain
#define QK_SCALE_L2E 0.12751744f

typedef short bf16x8 __attribute__((ext_vector_type(8)));
typedef float f32x4  __attribute__((ext_vector_type(4)));

__device__ __forceinline__ unsigned short f2bf(float f) {
    union { float f; unsigned u; } v; v.f = f;
    unsigned u = v.u;
    u += 0x7fffu + ((u >> 16) & 1u);           // RNE
    return (unsigned short)(u >> 16);
}
__device__ __forceinline__ float bf2f(unsigned short h) {
    union { unsigned u; float f; } v; v.u = ((unsigned)h) << 16;
    return v.f;
}
__device__ __forceinline__ unsigned cvt_pk_bf16(float a, float b) {
    unsigned r;
    asm("v_cvt_pk_bf16_f32 %0, %1, %2" : "=v"(r) : "v"(a), "v"(b));
    return r;   // low16 = bf16(a), high16 = bf16(b)
}

#define GLOAD_LDS16(g, l) __builtin_amdgcn_global_load_lds( \
    (const __attribute__((address_space(1))) void*)(g),     \
    (__attribute__((address_space(3))) void*)(l), 16, 0, 0)

// ---------------- converters ----------------

struct us4 { unsigned short a, b, c, d; };

__global__ __launch_bounds__(256)
void f32_to_bf16_vec(const float* __restrict__ in, unsigned short* __restrict__ out, long n) {
    long i = ((long)blockIdx.x * 256 + threadIdx.x) * 4;
    if (i < n) {
        float4 f = *(const float4*)(in + i);
        us4 o; o.a = f2bf(f.x); o.b = f2bf(f.y); o.c = f2bf(f.z); o.d = f2bf(f.w);
        *(us4*)(out + i) = o;
    }
}

// in: [R][C] f32 row-major  ->  out: [C][R] bf16 row-major
__global__ __launch_bounds__(256)
void transpose_w(const float* __restrict__ in, unsigned short* __restrict__ out, int R, int C) {
    __shared__ float tile[32][33];
    const int c0 = blockIdx.x * 32, r0 = blockIdx.y * 32;
    const int tx = threadIdx.x, ty = threadIdx.y;
#pragma unroll
    for (int i = 0; i < 4; ++i)
        tile[ty + i * 8][tx] = in[(long)(r0 + ty + i * 8) * C + c0 + tx];
    __syncthreads();
#pragma unroll
    for (int i = 0; i < 4; ++i)
        out[(long)(c0 + ty + i * 8) * R + r0 + tx] = f2bf(tile[tx][ty + i * 8]);
}

__global__ __launch_bounds__(256)
void rope_table(float* __restrict__ cosT, float* __restrict__ sinT) {
    const int idx = blockIdx.x * 256 + threadIdx.x;   // < 2048*64
    const int t = idx >> 6, d = idx & 63;
    const float inv = __expf(-(float)d * (9.210340371976184f / 64.0f)); // 10000^(-d/64)
    const float ang = (float)t * inv;
    cosT[idx] = cosf(ang);
    sinT[idx] = sinf(ang);
}

// in-place RoPE on q (heads 0..15, scaled by log2e/sqrt(hd)) and k (heads 16..19)
__global__ __launch_bounds__(256)
void rope_apply(unsigned short* __restrict__ qkv,
                const float* __restrict__ cosT, const float* __restrict__ sinT) {
    const int idx = blockIdx.x * 256 + threadIdx.x;   // 4096*20*64
    const int d = idx & 63;
    const int hh = (idx >> 6) % 20;
    const int row = idx / (64 * 20);
    const int t = row & (T_SEQ - 1);
    const int col = (hh < N_Q) ? hh * HD + d : DM + (hh - N_Q) * HD + d;
    unsigned short* p = qkv + (long)row * NQKV + col;
    const float a = bf2f(p[0]), b = bf2f(p[64]);
    const float c = cosT[t * 64 + d], s = sinT[t * 64 + d];
    float o1 = a * c - b * s;
    float o2 = b * c + a * s;
    if (hh < N_Q) { o1 *= QK_SCALE_L2E; o2 *= QK_SCALE_L2E; }
    p[0]  = f2bf(o1);
    p[64] = f2bf(o2);
}

// qkv v-cols [2560,3072) -> vt[b][hkv][d][t]
__global__ __launch_bounds__(256)
void transpose_v(const unsigned short* __restrict__ qkv, unsigned short* __restrict__ vt) {
    __shared__ unsigned short tile[32][33];
    const int bh = blockIdx.z;              // b*4 + hkv
    const int d0 = blockIdx.y * 32;
    const int t0 = blockIdx.x * 32;
    const int tx = threadIdx.x, ty = threadIdx.y;
    const long inbase = (long)(bh >> 2) * T_SEQ;
    const int coff = DM + N_KV * HD + (bh & 3) * HD;   // 2560 + hkv*128
#pragma unroll
    for (int i = 0; i < 4; ++i)
        tile[ty + i * 8][tx] = qkv[(inbase + t0 + ty + i * 8) * NQKV + coff + d0 + tx];
    __syncthreads();
#pragma unroll
    for (int i = 0; i < 4; ++i)
        vt[((long)bh * HD + d0 + ty + i * 8) * T_SEQ + t0 + tx] = tile[tx][ty + i * 8];
}

// ---------------- GEMM: 8-phase 256-row tile (T2+T3+T4+T5) ----------------
// C[M][ldc] = A[M][K] * Bt[N][K]^T.  512 threads = 8 waves (2M x 4N).
// BM=256, BN = 256 or 128, BK=64.  4 phases per K-tile:
//   p1: ds A-lo + B-lo            -> MFMA Q0 (fi 0-3 x fj-lo)
//   p2: ds B-hi                   -> MFMA Q1 (fi 0-3 x fj-hi)
//   p3: ds A-hi, stage B(t+2)     -> MFMA Q2 (fi 4-7 x fj-lo)
//   p4: stage A(t+2), vmcnt(TL)   -> MFMA Q3 (fi 4-7 x fj-hi)
// Tile t+2 staged into buf (t&1) after that buf's reads complete (B read by p2,
// A by p3); consumed 2 iters later; vmcnt(TL) at p4 covers tile t+1 (issued a
// full iteration earlier). vmcnt never drains to 0 in the loop.

template<int BN, int OUT_BF16>
__global__ __launch_bounds__(512, 2)
void gemm256(const unsigned short* __restrict__ A,
             const unsigned short* __restrict__ Bt,
             void* __restrict__ Cvoid, int K, int ldc) {
    constexpr int NFJ = BN / 64;          // frag-cols per wave (4 or 2)
    constexpr int HFJ = NFJ / 2;
    constexpr int HB  = BN / 2;           // rows per B half-tile
    constexpr int LB  = BN / 128;         // gloads/thread per B half (2 or 1)
    constexpr int TL  = 4 + 2 * LB;       // gloads/thread per K-tile (8 or 6)

    __shared__ __align__(16) unsigned short sA[2][2][128 * 64];
    __shared__ __align__(16) unsigned short sB[2][2][HB * 64];

    const int tid = threadIdx.x, lane = tid & 63, wid = tid >> 6;
    const int wm = wid >> 2, wn = wid & 3;
    const int lo = lane & 15, hi = lane >> 4;

    // XCD-aware bijective swizzle (nwg divisible by 8 in all launches)
    const int gx = gridDim.x;
    const int nwg = gx * gridDim.y;
    int flat = blockIdx.y * gx + blockIdx.x;
    flat = (flat & 7) * (nwg >> 3) + (flat >> 3);
    const long Row0 = (long)(flat / gx) * 256;
    const long Col0 = (long)(flat % gx) * BN;

    auto stageA = [&](int bb, int h, int kts) {
#pragma unroll
        for (int l = 0; l < 2; ++l) {
            const int cb = l * 512 + wid * 64;    // wave-uniform chunk base
            const int ck = cb + lane;
            const int row = ck >> 3;
            const int cs = (ck & 7) ^ (row & 7);  // pre-swizzled global source
            GLOAD_LDS16(A + (Row0 + h * 128 + row) * K + kts + cs * 8,
                        &sA[bb][h][cb * 8]);
        }
    };
    auto stageB = [&](int bb, int h, int kts) {
#pragma unroll
        for (int l = 0; l < LB; ++l) {
            const int cb = l * 512 + wid * 64;
            const int ck = cb + lane;
            const int row = ck >> 3;
            const int cs = (ck & 7) ^ (row & 7);
            GLOAD_LDS16(Bt + (Col0 + h * HB + row) * K + kts + cs * 8,
                        &sB[bb][h][cb * 8]);
        }
    };
    auto rdA = [&](int bb, int fi, int ks) -> bf16x8 {
        const int row = fi * 16 + lo;
        const int c = (ks * 4 + hi) ^ (row & 7);
        return *(const bf16x8*)&sA[bb][wm][row * 64 + c * 8];
    };
    auto rdB = [&](int bb, int fj, int ks) -> bf16x8 {
        const int rg = wn * (BN / 4) + fj * 16 + lo;   // output col in [0,BN)
        const int h = rg / HB;
        const int row = rg % HB;
        const int c = (ks * 4 + hi) ^ (row & 7);
        return *(const bf16x8*)&sB[bb][h][row * 64 + c * 8];
    };

    f32x4 acc[8][NFJ] = {};
    const int NT = K / 64;

    // prologue: stage tiles 0 and 1
    stageA(0, 0, 0);  stageA(0, 1, 0);  stageB(0, 0, 0);  stageB(0, 1, 0);
    stageA(1, 0, 64); stageA(1, 1, 64); stageB(1, 0, 64); stageB(1, 1, 64);
    if constexpr (TL == 8) asm volatile("s_waitcnt vmcnt(8)" ::: "memory");
    else                   asm volatile("s_waitcnt vmcnt(6)" ::: "memory");
    __builtin_amdgcn_s_barrier();

    for (int t = 0; t < NT; ++t) {
        const int bb = t & 1;
        int kts = (t + 2) * 64; if (kts >= K) kts -= K;   // wrapped: staged but unused at tail

        bf16x8 a_lo[4][2], a_hi[4][2], b_lo[HFJ][2], b_hi[HFJ][2];

        // ---- phase 1: read A-lo + B-lo; MFMA Q0 ----
#pragma unroll
        for (int fi = 0; fi < 4; ++fi) { a_lo[fi][0] = rdA(bb, fi, 0); a_lo[fi][1] = rdA(bb, fi, 1); }
#pragma unroll
        for (int fj = 0; fj < HFJ; ++fj) { b_lo[fj][0] = rdB(bb, fj, 0); b_lo[fj][1] = rdB(bb, fj, 1); }
        __builtin_amdgcn_s_barrier();
        asm volatile("s_waitcnt lgkmcnt(0)" ::: "memory");
        __builtin_amdgcn_sched_barrier(0);
        __builtin_amdgcn_s_setprio(1);
#pragma unroll
        for (int fi = 0; fi < 4; ++fi)
#pragma unroll
            for (int fj = 0; fj < HFJ; ++fj)
#pragma unroll
                for (int ks = 0; ks < 2; ++ks)
                    acc[fi][fj] = __builtin_amdgcn_mfma_f32_16x16x32_bf16(a_lo[fi][ks], b_lo[fj][ks], acc[fi][fj], 0, 0, 0);
        __builtin_amdgcn_s_setprio(0);
        __builtin_amdgcn_s_barrier();

        // ---- phase 2: read B-hi; MFMA Q1 ----
#pragma unroll
        for (int fj = 0; fj < HFJ; ++fj) { b_hi[fj][0] = rdB(bb, HFJ + fj, 0); b_hi[fj][1] = rdB(bb, HFJ + fj, 1); }
        __builtin_amdgcn_s_barrier();
        asm volatile("s_waitcnt lgkmcnt(0)" ::: "memory");
        __builtin_amdgcn_sched_barrier(0);
        __builtin_amdgcn_s_setprio(1);
#pragma unroll
        for (int fi = 0; fi < 4; ++fi)
#pragma unroll
            for (int fj = 0; fj < HFJ; ++fj)
#pragma unroll
                for (int ks = 0; ks < 2; ++ks)
                    acc[fi][HFJ + fj] = __builtin_amdgcn_mfma_f32_16x16x32_bf16(a_lo[fi][ks], b_hi[fj][ks], acc[fi][HFJ + fj], 0, 0, 0);
        __builtin_amdgcn_s_setprio(0);
        __builtin_amdgcn_s_barrier();

        // ---- phase 3: read A-hi; stage B(t+2); MFMA Q2 ----
#pragma unroll
        for (int fi = 0; fi < 4; ++fi) { a_hi[fi][0] = rdA(bb, 4 + fi, 0); a_hi[fi][1] = rdA(bb, 4 + fi, 1); }
        stageB(bb, 0, kts); stageB(bb, 1, kts);
        __builtin_amdgcn_s_barrier();
        asm volatile("s_waitcnt lgkmcnt(0)" ::: "memory");
        __builtin_amdgcn_sched_barrier(0);
        __builtin_amdgcn_s_setprio(1);
#pragma unroll
        for (int fi = 0; fi < 4; ++fi)
#pragma unroll
            for (int fj = 0; fj < HFJ; ++fj)
#pragma unroll
                for (int ks = 0; ks < 2; ++ks)
                    acc[4 + fi][fj] = __builtin_amdgcn_mfma_f32_16x16x32_bf16(a_hi[fi][ks], b_lo[fj][ks], acc[4 + fi][fj], 0, 0, 0);
        __builtin_amdgcn_s_setprio(0);
        __builtin_amdgcn_s_barrier();

        // ---- phase 4: stage A(t+2); counted vmcnt; MFMA Q3 ----
        stageA(bb, 0, kts); stageA(bb, 1, kts);
        if constexpr (TL == 8) asm volatile("s_waitcnt vmcnt(8)" ::: "memory");
        else                   asm volatile("s_waitcnt vmcnt(6)" ::: "memory");
        __builtin_amdgcn_s_barrier();
        __builtin_amdgcn_s_setprio(1);
#pragma unroll
        for (int fi = 0; fi < 4; ++fi)
#pragma unroll
            for (int fj = 0; fj < HFJ; ++fj)
#pragma unroll
                for (int ks = 0; ks < 2; ++ks)
                    acc[4 + fi][HFJ + fj] = __builtin_amdgcn_mfma_f32_16x16x32_bf16(a_hi[fi][ks], b_hi[fj][ks], acc[4 + fi][HFJ + fj], 0, 0, 0);
        __builtin_amdgcn_s_setprio(0);
        __builtin_amdgcn_s_barrier();
    }

    const long r0 = Row0 + wm * 128 + hi * 4;
    const long c0 = Col0 + wn * (BN / 4) + lo;
    if (OUT_BF16) {
        unsigned short* C = (unsigned short*)Cvoid;
#pragma unroll
        for (int fi = 0; fi < 8; ++fi)
#pragma unroll
            for (int fj = 0; fj < NFJ; ++fj)
#pragma unroll
                for (int r = 0; r < 4; ++r)
                    C[(r0 + fi * 16 + r) * ldc + c0 + fj * 16] = f2bf(acc[fi][fj][r]);
    } else {
        float* C = (float*)Cvoid;
#pragma unroll
        for (int fi = 0; fi < 8; ++fi)
#pragma unroll
            for (int fj = 0; fj < NFJ; ++fj)
#pragma unroll
                for (int r = 0; r < 4; ++r)
                    C[(r0 + fi * 16 + r) * ldc + c0 + fj * 16] = acc[fi][fj][r];
    }
}

// ---------------- flash attention, sliding window ----------------
// grid (T/64, N_Q, B), 4 waves x 16 q-rows, 64-key tiles
// swapped QK^T (S^T in regs, q-row lane-local softmax), exp2 domain,
// defer-max, double-buffered K/V staging.

__global__ __launch_bounds__(256)
void attn_kernel(const unsigned short* __restrict__ qkv,
                 const unsigned short* __restrict__ vt,
                 unsigned short* __restrict__ aout) {
    const int qt = blockIdx.x, h = blockIdx.y, b = blockIdx.z;
    const int tid = threadIdx.x, lane = tid & 63, w = tid >> 6;
    const int q0w = qt * 64 + w * 16;
    const int hkv = h >> 2;
    const int lo = lane & 15, hi = lane >> 4;

    __shared__ __align__(16) unsigned short sK[2][64 * 128];   // [key][d], chunk-swizzled
    __shared__ __align__(16) unsigned short sV[2][128 * 64];   // [d][key], chunk-swizzled
    __shared__ __align__(16) unsigned short plds[4][16 * 64];  // per-wave P, [q][key^swz]
    unsigned short* pl = plds[w];

    bf16x8 qf[4];
    {
        const unsigned short* qp = qkv + (long)(b * T_SEQ + q0w + lo) * NQKV + h * HD + hi * 8;
#pragma unroll
        for (int s = 0; s < 4; ++s) qf[s] = *(const bf16x8*)(qp + s * 32);
    }

    f32x4 of[8] = {};
    float m_r = -1e30f;   // running max for q = q0w + lo (log2 domain)
    float s_r = 0.f;      // running denom for q = q0w + lo

    int kstart = qt * 64 - (WIN - 1);
    if (kstart < 0) kstart = 0;
    kstart &= ~63;
    const int kend = qt * 64 + 63;

    const unsigned short* kbase = qkv + (long)b * T_SEQ * NQKV + DM + hkv * HD;
    const unsigned short* vbase = vt + (long)(b * N_KV + hkv) * HD * T_SEQ;

    // staging offsets (pre-swizzled global source, linear LDS dest)
    int krow[4], kck[4], vrow[4], vck[4];
#pragma unroll
    for (int u = 0; u < 4; ++u) {
        const int i = w * 4 + u;
        krow[u] = i * 4 + (lane >> 4);
        kck[u]  = (lane & 15) ^ (krow[u] & 7);
        vrow[u] = i * 8 + (lane >> 3);
        vck[u]  = (lane & 7) ^ (vrow[u] & 7);
    }

#define STAGE(bf, kt_) do {                                                          \
    _Pragma("unroll")                                                                \
    for (int u = 0; u < 4; ++u) {                                                    \
        const int i = w * 4 + u;                                                     \
        GLOAD_LDS16(kbase + (long)((kt_) + krow[u]) * NQKV + kck[u] * 8, &sK[bf][i * 512]); \
        GLOAD_LDS16(vbase + (long)vrow[u] * T_SEQ + (kt_) + vck[u] * 8, &sV[bf][i * 512]);  \
    } } while (0)

    STAGE(0, kstart);
    asm volatile("s_waitcnt vmcnt(0)" ::: "memory");
    __syncthreads();

    int buf = 0;
    for (int kt = kstart; kt <= kend; kt += 64) {
        if (kt + 64 <= kend) STAGE(buf ^ 1, kt + 64);

        // ---- swapped QK^T: sf[n][r] = S^T[key = kt+n*16+hi*4+r][q = q0w+lo] ----
        f32x4 sf[4] = {};
        __builtin_amdgcn_s_setprio(1);
#pragma unroll
        for (int n = 0; n < 4; ++n) {
            const int row = n * 16 + lo;
#pragma unroll
            for (int s = 0; s < 4; ++s) {
                const int c = (s * 4 + hi) ^ (row & 7);
                bf16x8 kf = *(const bf16x8*)&sK[buf][row * 128 + c * 8];
                sf[n] = __builtin_amdgcn_mfma_f32_16x16x32_bf16(kf, qf[s], sf[n], 0, 0, 0);
            }
        }
        __builtin_amdgcn_s_setprio(0);

        // ---- lane-local online softmax (q = q0w + lo) ----
        const int q = q0w + lo;
        float sv[4][4];
        float mx = -1e30f;
#pragma unroll
        for (int n = 0; n < 4; ++n)
#pragma unroll
            for (int r = 0; r < 4; ++r) {
                const int d = q - (kt + n * 16 + hi * 4 + r);
                sv[n][r] = (d >= 0 && d < WIN) ? sf[n][r] : -1e30f;
                mx = fmaxf(mx, sv[n][r]);
            }
        mx = fmaxf(mx, __shfl_xor(mx, 16));
        mx = fmaxf(mx, __shfl_xor(mx, 32));

        if (!__all(mx <= m_r + 8.0f)) {           // defer-max: rescale rarely
            const float mnew = fmaxf(m_r, mx);
            const float resc = exp2f(m_r - mnew);
            s_r *= resc;
            m_r = mnew;
            float r4[4];
#pragma unroll
            for (int r = 0; r < 4; ++r) r4[r] = __shfl(resc, hi * 4 + r);
#pragma unroll
            for (int j = 0; j < 8; ++j) {
                of[j][0] *= r4[0]; of[j][1] *= r4[1];
                of[j][2] *= r4[2]; of[j][3] *= r4[3];
            }
        }

        float pv[4][4];
        float psum = 0.f;
#pragma unroll
        for (int n = 0; n < 4; ++n)
#pragma unroll
            for (int r = 0; r < 4; ++r) {
                pv[n][r] = exp2f(sv[n][r] - m_r);
                psum += pv[n][r];
            }
        psum += __shfl_xor(psum, 16);
        psum += __shfl_xor(psum, 32);
        s_r += psum;

        // ---- pack P -> per-wave swizzled LDS (u32 writes, cvt_pk) ----
        const int swz = (lo & 7) << 3;
#pragma unroll
        for (int n = 0; n < 4; ++n) {
            const int k0 = n * 16 + hi * 4;
            *(unsigned*)&pl[lo * 64 + (k0 ^ swz)]       = cvt_pk_bf16(pv[n][0], pv[n][1]);
            *(unsigned*)&pl[lo * 64 + ((k0 + 2) ^ swz)] = cvt_pk_bf16(pv[n][2], pv[n][3]);
        }
        asm volatile("s_waitcnt lgkmcnt(0)" ::: "memory");
        __builtin_amdgcn_sched_barrier(0);
        bf16x8 pa[2];
#pragma unroll
        for (int ks = 0; ks < 2; ++ks) {
            const int c = (ks * 4 + hi) ^ (lo & 7);
            pa[ks] = *(const bf16x8*)&pl[lo * 64 + c * 8];
        }

        // ---- PV: of[j][r] += P[q=hi*4+r] · V[d=j*16+lo] ----
        __builtin_amdgcn_s_setprio(1);
#pragma unroll
        for (int j = 0; j < 8; ++j) {
            const int row = j * 16 + lo;
#pragma unroll
            for (int ks = 0; ks < 2; ++ks) {
                const int c = (ks * 4 + hi) ^ (row & 7);
                bf16x8 vf = *(const bf16x8*)&sV[buf][row * 64 + c * 8];
                of[j] = __builtin_amdgcn_mfma_f32_16x16x32_bf16(pa[ks], vf, of[j], 0, 0, 0);
            }
        }
        __builtin_amdgcn_s_setprio(0);

        asm volatile("s_waitcnt vmcnt(0)" ::: "memory");
        __syncthreads();
        buf ^= 1;
    }
#undef STAGE

    float s4[4];
#pragma unroll
    for (int r = 0; r < 4; ++r) s4[r] = __shfl(s_r, hi * 4 + r);
#pragma unroll
    for (int r = 0; r < 4; ++r) {
        const int qrow = q0w + hi * 4 + r;
        const float inv = 1.0f / s4[r];
        unsigned short* op = aout + (long)(b * T_SEQ + qrow) * DM + h * HD + lo;
#pragma unroll
        for (int j = 0; j < 8; ++j) op[j * 16] = f2bf(of[j][r] * inv);
    }
}

// ---------------- launch ----------------

extern "C" void kernel_launch(void* const* d_in, const int* in_sizes, int n_in,
                              void* d_out, int out_size, void* d_ws, size_t ws_size,
                              hipStream_t stream) {
    (void)in_sizes; (void)n_in; (void)out_size; (void)ws_size;
    const float* x  = (const float*)d_in[0];
    const float* wq = (const float*)d_in[1];
    const float* wk = (const float*)d_in[2];
    const float* wv = (const float*)d_in[3];
    const float* wo = (const float*)d_in[4];
    float* out = (float*)d_out;
    char* ws = (char*)d_ws;

    unsigned short* xbf   = (unsigned short*)(ws);                // 16,777,216 B
    unsigned short* wqkvT = (unsigned short*)(ws + 16777216);     // 12,582,912 B
    unsigned short* woT   = (unsigned short*)(ws + 29360128);     //  8,388,608 B
    unsigned short* qkv   = (unsigned short*)(ws + 37748736);     // 25,165,824 B
    unsigned short* vt    = (unsigned short*)(ws + 62914560);     //  4,194,304 B
    unsigned short* aout  = (unsigned short*)(ws + 67108864);     // 16,777,216 B
    float* cosT = (float*)(ws + 83886080);                        //    524,288 B
    float* sinT = (float*)(ws + 84410368);                        //    524,288 B

    const long Mx = (long)NB * T_SEQ * DM;                        // x elements
    f32_to_bf16_vec<<<dim3(8192), dim3(256), 0, stream>>>(x, xbf, Mx);
    transpose_w<<<dim3(64, 64), dim3(32, 8), 0, stream>>>(wq, wqkvT, DM, DM);
    transpose_w<<<dim3(16, 64), dim3(32, 8), 0, stream>>>(wk, wqkvT + (long)DM * DM, DM, 512);
    transpose_w<<<dim3(16, 64), dim3(32, 8), 0, stream>>>(wv, wqkvT + (long)(DM + 512) * DM, DM, 512);
    transpose_w<<<dim3(64, 64), dim3(32, 8), 0, stream>>>(wo, woT, DM, DM);
    rope_table<<<dim3(512), dim3(256), 0, stream>>>(cosT, sinT);

    gemm256<256, 1><<<dim3(NQKV / 256, 16), dim3(512), 0, stream>>>(xbf, wqkvT, qkv, DM, NQKV);
    rope_apply<<<dim3(20480), dim3(256), 0, stream>>>(qkv, cosT, sinT);
    transpose_v<<<dim3(64, 4, 8), dim3(32, 8), 0, stream>>>(qkv, vt);
    attn_kernel<<<dim3(32, 16, 2), dim3(256), 0, stream>>>(qkv, vt, aout);
    gemm256<128, 0><<<dim3(DM / 128, 16), dim3(512), 0, stream>>>(aout, woT, out, DM, DM);
}

// Round 5
// 174.630 us; speedup vs baseline: 1.1881x; 1.1881x over previous
//
#include <hip/hip_runtime.h>

#define T_SEQ   2048
#define DM      2048
#define N_Q     16
#define N_KV    4
#define HD      128
#define WIN     512
#define NB      2
#define NQKV    3072
// 1/sqrt(128) * log2(e): attention computed in exp2 domain
#define QK_SCALE_L2E 0.12751744f

typedef short bf16x8 __attribute__((ext_vector_type(8)));
typedef float f32x4  __attribute__((ext_vector_type(4)));
typedef unsigned short us4v __attribute__((ext_vector_type(4)));

__device__ __forceinline__ unsigned short f2bf(float f) {
    union { float f; unsigned u; } v; v.f = f;
    unsigned u = v.u;
    u += 0x7fffu + ((u >> 16) & 1u);           // RNE
    return (unsigned short)(u >> 16);
}
__device__ __forceinline__ float bf2f(unsigned short h) {
    union { unsigned u; float f; } v; v.u = ((unsigned)h) << 16;
    return v.f;
}
__device__ __forceinline__ unsigned cvt_pk_bf16(float a, float b) {
    unsigned r;
    asm("v_cvt_pk_bf16_f32 %0, %1, %2" : "=v"(r) : "v"(a), "v"(b));
    return r;   // low16 = bf16(a), high16 = bf16(b)
}

#define GLOAD_LDS16(g, l) __builtin_amdgcn_global_load_lds( \
    (const __attribute__((address_space(1))) void*)(g),     \
    (__attribute__((address_space(3))) void*)(l), 16, 0, 0)

// ---------------- converters ----------------

struct us4 { unsigned short a, b, c, d; };

__global__ __launch_bounds__(256)
void f32_to_bf16_vec(const float* __restrict__ in, unsigned short* __restrict__ out, long n) {
    long i = ((long)blockIdx.x * 256 + threadIdx.x) * 4;
    if (i < n) {
        float4 f = *(const float4*)(in + i);
        us4 o; o.a = f2bf(f.x); o.b = f2bf(f.y); o.c = f2bf(f.z); o.d = f2bf(f.w);
        *(us4*)(out + i) = o;
    }
}

// all 4 weights transposed in one launch: z selects the weight
__global__ __launch_bounds__(256)
void transpose_w_all(const float* __restrict__ wq, const float* __restrict__ wk,
                     const float* __restrict__ wv, const float* __restrict__ wo,
                     unsigned short* __restrict__ wqkvT, unsigned short* __restrict__ woT) {
    __shared__ float tile[32][33];
    const int z = blockIdx.z;
    const float* in; unsigned short* out; int C;
    if (z == 0)      { in = wq; out = wqkvT;                        C = DM;  }
    else if (z == 1) { in = wk; out = wqkvT + (long)DM * DM;        C = 512; }
    else if (z == 2) { in = wv; out = wqkvT + (long)(DM + 512) * DM; C = 512; }
    else             { in = wo; out = woT;                          C = DM;  }
    const int c0 = blockIdx.x * 32, r0 = blockIdx.y * 32;
    if (c0 >= C) return;
    const int tx = threadIdx.x, ty = threadIdx.y;
#pragma unroll
    for (int i = 0; i < 4; ++i)
        tile[ty + i * 8][tx] = in[(long)(r0 + ty + i * 8) * C + c0 + tx];
    __syncthreads();
#pragma unroll
    for (int i = 0; i < 4; ++i)
        out[(long)(c0 + ty + i * 8) * DM + r0 + tx] = f2bf(tile[tx][ty + i * 8]);
}

__global__ __launch_bounds__(256)
void rope_table(float* __restrict__ cosT, float* __restrict__ sinT) {
    const int idx = blockIdx.x * 256 + threadIdx.x;   // < 2048*64
    const int t = idx >> 6, d = idx & 63;
    const float inv = __expf(-(float)d * (9.210340371976184f / 64.0f)); // 10000^(-d/64)
    const float ang = (float)t * inv;
    cosT[idx] = cosf(ang);
    sinT[idx] = sinf(ang);
}

// in-place RoPE on q (heads 0..15, scaled by log2e/sqrt(hd)) and k (heads 16..19)
// vectorized: 4 d-values per thread
__global__ __launch_bounds__(256)
void rope_apply(unsigned short* __restrict__ qkv,
                const float* __restrict__ cosT, const float* __restrict__ sinT) {
    const int idx = blockIdx.x * 256 + threadIdx.x;   // 4096*20*16
    const int d4 = (idx & 15) * 4;
    const int hh = (idx >> 4) % 20;
    const int row = idx / (16 * 20);
    const int t = row & (T_SEQ - 1);
    const int col = (hh < N_Q) ? hh * HD + d4 : DM + (hh - N_Q) * HD + d4;
    unsigned short* p = qkv + (long)row * NQKV + col;
    us4v a = *(const us4v*)p;
    us4v b = *(const us4v*)(p + 64);
    float4 c = *(const float4*)&cosT[t * 64 + d4];
    float4 s = *(const float4*)&sinT[t * 64 + d4];
    const float sc = (hh < N_Q) ? QK_SCALE_L2E : 1.0f;
    us4v o1, o2;
    const float cc[4] = { c.x, c.y, c.z, c.w }, ss[4] = { s.x, s.y, s.z, s.w };
#pragma unroll
    for (int i = 0; i < 4; ++i) {
        const float av = bf2f(a[i]), bv = bf2f(b[i]);
        o1[i] = f2bf((av * cc[i] - bv * ss[i]) * sc);
        o2[i] = f2bf((bv * cc[i] + av * ss[i]) * sc);
    }
    *(us4v*)p        = o1;
    *(us4v*)(p + 64) = o2;
}

// qkv v-cols [2560,3072) -> vt[b][hkv][d][t]
__global__ __launch_bounds__(256)
void transpose_v(const unsigned short* __restrict__ qkv, unsigned short* __restrict__ vt) {
    __shared__ unsigned short tile[32][33];
    const int bh = blockIdx.z;              // b*4 + hkv
    const int d0 = blockIdx.y * 32;
    const int t0 = blockIdx.x * 32;
    const int tx = threadIdx.x, ty = threadIdx.y;
    const long inbase = (long)(bh >> 2) * T_SEQ;
    const int coff = DM + N_KV * HD + (bh & 3) * HD;   // 2560 + hkv*128
#pragma unroll
    for (int i = 0; i < 4; ++i)
        tile[ty + i * 8][tx] = qkv[(inbase + t0 + ty + i * 8) * NQKV + coff + d0 + tx];
    __syncthreads();
#pragma unroll
    for (int i = 0; i < 4; ++i)
        vt[((long)bh * HD + d0 + ty + i * 8) * T_SEQ + t0 + tx] = tile[tx][ty + i * 8];
}

// ---------------- GEMM: C[M][ldc] = A[M][K] * Bt[N][K]^T  (m97 structure + XCD swizzle) ----------------

template<int OUT_BF16>
__global__ __launch_bounds__(256)
void gemm_bt(const unsigned short* __restrict__ A,
             const unsigned short* __restrict__ Bt,
             void* __restrict__ Cvoid, int K, int ldc) {
    __shared__ __align__(16) unsigned short sA[128 * 64];
    __shared__ __align__(16) unsigned short sB[128 * 64];
    const int tid = threadIdx.x;
    const int lane = tid & 63;
    const int wid = tid >> 6;
    const int wr = (wid >> 1) * 64, wc = (wid & 1) * 64;

    // XCD-aware bijective swizzle (nwg divisible by 8 in all launches)
    const int gx = gridDim.x;
    const int nwg = gx * gridDim.y;
    int flat = blockIdx.y * gx + blockIdx.x;
    flat = (flat & 7) * (nwg >> 3) + (flat >> 3);
    const long Arow0 = (long)(flat / gx) * 128;
    const long Brow0 = (long)(flat % gx) * 128;

    f32x4 acc[4][4] = {};

    for (int kt = 0; kt < K; kt += 64) {
        __syncthreads();
#pragma unroll
        for (int n = 0; n < 4; ++n) {
            const int linb = n * 256 + wid * 64;      // wave-uniform 16B-chunk base
            const int lin  = linb + lane;             // this lane's chunk
            const int row  = lin >> 3;                // 8 chunks per 64-elem row
            const int sc   = (lin & 7) ^ (row & 7);   // pre-swizzled global source
            const unsigned short* gA = A  + (Arow0 + row) * K + kt + sc * 8;
            const unsigned short* gB = Bt + (Brow0 + row) * K + kt + sc * 8;
            GLOAD_LDS16(gA, &sA[linb * 8]);
            GLOAD_LDS16(gB, &sB[linb * 8]);
        }
        __syncthreads();
#pragma unroll
        for (int kk = 0; kk < 2; ++kk) {
            bf16x8 av[4], bv[4];
#pragma unroll
            for (int i = 0; i < 4; ++i) {
                const int row = wr + i * 16 + (lane & 15);
                const int c = (kk * 4 + (lane >> 4)) ^ (row & 7);
                av[i] = *(const bf16x8*)&sA[row * 64 + c * 8];
            }
#pragma unroll
            for (int j = 0; j < 4; ++j) {
                const int row = wc + j * 16 + (lane & 15);
                const int c = (kk * 4 + (lane >> 4)) ^ (row & 7);
                bv[j] = *(const bf16x8*)&sB[row * 64 + c * 8];
            }
#pragma unroll
            for (int i = 0; i < 4; ++i)
#pragma unroll
                for (int j = 0; j < 4; ++j)
                    acc[i][j] = __builtin_amdgcn_mfma_f32_16x16x32_bf16(av[i], bv[j], acc[i][j], 0, 0, 0);
        }
    }

    const int r0 = (int)Arow0 + wr + ((lane >> 4) << 2);
    const int c0 = (int)Brow0 + wc + (lane & 15);
    if (OUT_BF16) {
        unsigned short* C = (unsigned short*)Cvoid;
#pragma unroll
        for (int i = 0; i < 4; ++i)
#pragma unroll
            for (int j = 0; j < 4; ++j)
#pragma unroll
                for (int r = 0; r < 4; ++r)
                    C[(long)(r0 + i * 16 + r) * ldc + c0 + j * 16] = f2bf(acc[i][j][r]);
    } else {
        float* C = (float*)Cvoid;
#pragma unroll
        for (int i = 0; i < 4; ++i)
#pragma unroll
            for (int j = 0; j < 4; ++j)
#pragma unroll
                for (int r = 0; r < 4; ++r)
                    C[(long)(r0 + i * 16 + r) * ldc + c0 + j * 16] = acc[i][j][r];
    }
}

// ---------------- flash attention, sliding window ----------------
// grid (T/64, N_KV, B), 512 threads = 8 waves.
// wave w: q-head = hkv*4 + (w&3), q-rows = qt*64 + (w>>2)*32 + [0,32).
// All 8 waves share the staged K/V tiles (4 q-heads x 2 q-halves).
// Swapped QK^T (S^T in regs, lane-local softmax), exp2 domain, defer-max,
// double-buffered K/V staging via global_load_lds.

__global__ __launch_bounds__(512, 2)
void attn_kernel(const unsigned short* __restrict__ qkv,
                 const unsigned short* __restrict__ vt,
                 unsigned short* __restrict__ aout) {
    const int qt = blockIdx.x, hkv = blockIdx.y, b = blockIdx.z;
    const int tid = threadIdx.x, lane = tid & 63, w = tid >> 6;
    const int qh = hkv * 4 + (w & 3);          // q-head for this wave
    const int qsub = w >> 2;                   // 0 or 1: which 32-row half
    const int q0w = qt * 64 + qsub * 32;       // wave's first q-row
    const int lo = lane & 15, hi = lane >> 4;

    __shared__ __align__(16) unsigned short sK[2][64 * 128];   // [key][d], chunk-swizzled
    __shared__ __align__(16) unsigned short sV[2][128 * 64];   // [d][key], chunk-swizzled
    __shared__ __align__(16) unsigned short plds[8][32 * 64];  // per-wave P, [q][key^swz]
    unsigned short* pl = plds[w];

    // Q fragments: 2 q-frags x 4 k-chunks
    bf16x8 qf2[2][4];
#pragma unroll
    for (int f = 0; f < 2; ++f) {
        const unsigned short* qp = qkv + (long)(b * T_SEQ + q0w + f * 16 + lo) * NQKV + qh * HD + hi * 8;
#pragma unroll
        for (int s = 0; s < 4; ++s) qf2[f][s] = *(const bf16x8*)(qp + s * 32);
    }

    f32x4 of[8][2] = {};
    float m_r[2] = { -1e30f, -1e30f };   // running max for q = q0w + f*16 + lo
    float s_r[2] = { 0.f, 0.f };

    int kstart = qt * 64 - (WIN - 1);
    if (kstart < 0) kstart = 0;
    kstart &= ~63;
    const int kend = qt * 64 + 63;

    const unsigned short* kbase = qkv + (long)b * T_SEQ * NQKV + DM + hkv * HD;
    const unsigned short* vbase = vt + (long)(b * N_KV + hkv) * HD * T_SEQ;

    // staging offsets (pre-swizzled global source, linear LDS dest); 512 thr x 2 chunks each
    int kr[2], kc[2], vr[2], vc[2];
#pragma unroll
    for (int u = 0; u < 2; ++u) {
        const int c = u * 512 + tid;
        kr[u] = c >> 4;  kc[u] = (c & 15) ^ (kr[u] & 7);   // sK: 16 chunks/row
        vr[u] = c >> 3;  vc[u] = (c & 7) ^ (vr[u] & 7);    // sV: 8 chunks/row
    }

#define STAGE(bf, kt_) do {                                                              \
    _Pragma("unroll")                                                                    \
    for (int u = 0; u < 2; ++u) {                                                        \
        const int dbase = (u * 512 + w * 64) * 8;                                        \
        GLOAD_LDS16(kbase + (long)((kt_) + kr[u]) * NQKV + kc[u] * 8, &sK[bf][dbase]);   \
        GLOAD_LDS16(vbase + (long)vr[u] * T_SEQ + (kt_) + vc[u] * 8, &sV[bf][dbase]);    \
    } } while (0)

    STAGE(0, kstart);
    asm volatile("s_waitcnt vmcnt(0)" ::: "memory");
    __syncthreads();

    int buf = 0;
    for (int kt = kstart; kt <= kend; kt += 64) {
        if (kt + 64 <= kend) STAGE(buf ^ 1, kt + 64);

        // ---- swapped QK^T: sf[n][f] = S^T[key = kt+n*16+...][q = q0w+f*16+lo] ----
        f32x4 sf[4][2] = {};
        __builtin_amdgcn_s_setprio(1);
#pragma unroll
        for (int n = 0; n < 4; ++n) {
            const int row = n * 16 + lo;
#pragma unroll
            for (int s = 0; s < 4; ++s) {
                const int c = (s * 4 + hi) ^ (row & 7);
                bf16x8 kf = *(const bf16x8*)&sK[buf][row * 128 + c * 8];
                sf[n][0] = __builtin_amdgcn_mfma_f32_16x16x32_bf16(kf, qf2[0][s], sf[n][0], 0, 0, 0);
                sf[n][1] = __builtin_amdgcn_mfma_f32_16x16x32_bf16(kf, qf2[1][s], sf[n][1], 0, 0, 0);
            }
        }
        __builtin_amdgcn_s_setprio(0);

        // ---- lane-local online softmax, 2 q-frags ----
        float pv[2][4][4];
        float mx[2] = { -1e30f, -1e30f };
#pragma unroll
        for (int f = 0; f < 2; ++f) {
            const int q = q0w + f * 16 + lo;
#pragma unroll
            for (int n = 0; n < 4; ++n)
#pragma unroll
                for (int r = 0; r < 4; ++r) {
                    const int d = q - (kt + n * 16 + hi * 4 + r);
                    pv[f][n][r] = (d >= 0 && d < WIN) ? sf[n][f][r] : -1e30f;
                    mx[f] = fmaxf(mx[f], pv[f][n][r]);
                }
            mx[f] = fmaxf(mx[f], __shfl_xor(mx[f], 16));
            mx[f] = fmaxf(mx[f], __shfl_xor(mx[f], 32));
        }

        const bool ok = (mx[0] <= m_r[0] + 8.0f) && (mx[1] <= m_r[1] + 8.0f);
        if (!__all(ok)) {                          // defer-max: rescale rarely
#pragma unroll
            for (int f = 0; f < 2; ++f) {
                const float mnew = fmaxf(m_r[f], mx[f]);
                const float resc = exp2f(m_r[f] - mnew);
                s_r[f] *= resc;
                m_r[f] = mnew;
                float r4[4];
#pragma unroll
                for (int r = 0; r < 4; ++r) r4[r] = __shfl(resc, hi * 4 + r);
#pragma unroll
                for (int j = 0; j < 8; ++j) {
                    of[j][f][0] *= r4[0]; of[j][f][1] *= r4[1];
                    of[j][f][2] *= r4[2]; of[j][f][3] *= r4[3];
                }
            }
        }

#pragma unroll
        for (int f = 0; f < 2; ++f) {
            float psum = 0.f;
#pragma unroll
            for (int n = 0; n < 4; ++n)
#pragma unroll
                for (int r = 0; r < 4; ++r) {
                    pv[f][n][r] = exp2f(pv[f][n][r] - m_r[f]);
                    psum += pv[f][n][r];
                }
            psum += __shfl_xor(psum, 16);
            psum += __shfl_xor(psum, 32);
            s_r[f] += psum;
        }

        // ---- pack P -> per-wave swizzled LDS (u32 writes, cvt_pk) ----
        const int swz = (lo & 7) << 3;
#pragma unroll
        for (int f = 0; f < 2; ++f) {
            const int rowq = f * 16 + lo;
#pragma unroll
            for (int n = 0; n < 4; ++n) {
                const int k0 = n * 16 + hi * 4;
                *(unsigned*)&pl[rowq * 64 + (k0 ^ swz)]       = cvt_pk_bf16(pv[f][n][0], pv[f][n][1]);
                *(unsigned*)&pl[rowq * 64 + ((k0 + 2) ^ swz)] = cvt_pk_bf16(pv[f][n][2], pv[f][n][3]);
            }
        }
        asm volatile("s_waitcnt lgkmcnt(0)" ::: "memory");
        __builtin_amdgcn_sched_barrier(0);
        bf16x8 pa2[2][2];
#pragma unroll
        for (int f = 0; f < 2; ++f)
#pragma unroll
            for (int ks = 0; ks < 2; ++ks) {
                const int c = (ks * 4 + hi) ^ (lo & 7);
                pa2[f][ks] = *(const bf16x8*)&pl[(f * 16 + lo) * 64 + c * 8];
            }

        // ---- PV: of[j][f] += P[q-frag f] . V[d=j*16+lo] ----
        __builtin_amdgcn_s_setprio(1);
#pragma unroll
        for (int j = 0; j < 8; ++j) {
            const int row = j * 16 + lo;
#pragma unroll
            for (int ks = 0; ks < 2; ++ks) {
                const int c = (ks * 4 + hi) ^ (row & 7);
                bf16x8 vf = *(const bf16x8*)&sV[buf][row * 64 + c * 8];
                of[j][0] = __builtin_amdgcn_mfma_f32_16x16x32_bf16(pa2[0][ks], vf, of[j][0], 0, 0, 0);
                of[j][1] = __builtin_amdgcn_mfma_f32_16x16x32_bf16(pa2[1][ks], vf, of[j][1], 0, 0, 0);
            }
        }
        __builtin_amdgcn_s_setprio(0);

        asm volatile("s_waitcnt vmcnt(0)" ::: "memory");
        __syncthreads();
        buf ^= 1;
    }
#undef STAGE

#pragma unroll
    for (int f = 0; f < 2; ++f) {
        float s4[4];
#pragma unroll
        for (int r = 0; r < 4; ++r) s4[r] = __shfl(s_r[f], hi * 4 + r);
#pragma unroll
        for (int r = 0; r < 4; ++r) {
            const int qrow = q0w + f * 16 + hi * 4 + r;
            const float inv = 1.0f / s4[r];
            unsigned short* op = aout + (long)(b * T_SEQ + qrow) * DM + qh * HD + lo;
#pragma unroll
            for (int j = 0; j < 8; ++j) op[j * 16] = f2bf(of[j][f][r] * inv);
        }
    }
}

// ---------------- launch ----------------

extern "C" void kernel_launch(void* const* d_in, const int* in_sizes, int n_in,
                              void* d_out, int out_size, void* d_ws, size_t ws_size,
                              hipStream_t stream) {
    (void)in_sizes; (void)n_in; (void)out_size; (void)ws_size;
    const float* x  = (const float*)d_in[0];
    const float* wq = (const float*)d_in[1];
    const float* wk = (const float*)d_in[2];
    const float* wv = (const float*)d_in[3];
    const float* wo = (const float*)d_in[4];
    float* out = (float*)d_out;
    char* ws = (char*)d_ws;

    unsigned short* xbf   = (unsigned short*)(ws);                // 16,777,216 B
    unsigned short* wqkvT = (unsigned short*)(ws + 16777216);     // 12,582,912 B
    unsigned short* woT   = (unsigned short*)(ws + 29360128);     //  8,388,608 B
    unsigned short* qkv   = (unsigned short*)(ws + 37748736);     // 25,165,824 B
    unsigned short* vt    = (unsigned short*)(ws + 62914560);     //  4,194,304 B
    unsigned short* aout  = (unsigned short*)(ws + 67108864);     // 16,777,216 B
    float* cosT = (float*)(ws + 83886080);                        //    524,288 B
    float* sinT = (float*)(ws + 84410368);                        //    524,288 B

    const long Mx = (long)NB * T_SEQ * DM;                        // x elements
    f32_to_bf16_vec<<<dim3(8192), dim3(256), 0, stream>>>(x, xbf, Mx);
    transpose_w_all<<<dim3(64, 64, 4), dim3(32, 8), 0, stream>>>(wq, wk, wv, wo, wqkvT, woT);
    rope_table<<<dim3(512), dim3(256), 0, stream>>>(cosT, sinT);

    gemm_bt<1><<<dim3(NQKV / 128, 32), dim3(256), 0, stream>>>(xbf, wqkvT, qkv, DM, NQKV);
    rope_apply<<<dim3(5120), dim3(256), 0, stream>>>(qkv, cosT, sinT);
    transpose_v<<<dim3(64, 4, 8), dim3(32, 8), 0, stream>>>(qkv, vt);
    attn_kernel<<<dim3(32, 4, 2), dim3(512), 0, stream>>>(qkv, vt, aout);
    gemm_bt<0><<<dim3(DM / 128, 32), dim3(256), 0, stream>>>(aout, woT, out, DM, DM);
}